// Round 2
// baseline (3077.532 us; speedup 1.0000x reference)
//
#include <hip/hip_runtime.h>
#include <cstddef>

// SimpleLSTM: B=64, D=512, T=512, H=1024, O=1 — fp16, packed block-flags, 1 barrier/step
// ws layout (~46.53 MB):
//   [0, 32MB)            xT: f16 [T=512][B=64][D=512]
//   [32MB, +12.58MB)     Wf: f16 A-frags [r=64][ks=48][mt=4][lane=64][8]
//                        (reused after weight load as out-partials
//                         part[t=512][g=4][r=64][b16=16] f32 = 8MB, atomicAdd'd)
//   [46,137,344, +256KB) h double buffer: f16 [2][B=64][H=1024]
//   [46,399,488, +128KB) flags[g=4][r=64] u32 CONTIGUOUS (1 flag per producer block;
//                        consumer wave w polls flags[g*64+8w..+8) = one 128B line)
//                        + ready counter at index 32768
#define WS_XT_OFF   0ull
#define WS_WF_OFF   33554432ull
#define WS_HB_OFF   46137344ull
#define WS_CTR_OFF  46399488ull

typedef _Float16 f16x8 __attribute__((ext_vector_type(8)));
typedef float    f32x4 __attribute__((ext_vector_type(4)));
typedef unsigned short u16;
typedef unsigned int   u32;
typedef unsigned long long u64;

__device__ __forceinline__ u16 f2h(float f) {
  _Float16 h = (_Float16)f;                     // v_cvt_f16_f32, RNE
  return __builtin_bit_cast(u16, h);
}
// Fast gate math: v_exp + v_rcp (no IEEE div, no branchy ocml tanh).
// Robust at extremes: x->+inf: exp(-x)=0 -> rcp(1)=1; x->-inf: rcp(inf)=0.
__device__ __forceinline__ float sigm(float x) {
  return __builtin_amdgcn_rcpf(1.0f + __expf(-x));
}
// tanh(x) = 1 - 2/(exp(2x)+1); x->+inf: rcp(inf)=0 -> 1; x->-inf: 1-2 = -1.
__device__ __forceinline__ float tanh_fast(float x) {
  return 1.0f - 2.0f * __builtin_amdgcn_rcpf(__expf(2.0f * x) + 1.0f);
}

// ---------- K0: init h buf0 = 0, flags/ready = 0 ----------
__global__ __launch_bounds__(256) void k_init(u16* hbuf, u32* ctrs) {
  int t = blockIdx.x * 256 + threadIdx.x;       // 32768 threads
  ((u32*)hbuf)[t] = 0u;                         // zeroes buf0 (131072 B)
  ctrs[t] = 0u;                                 // covers flags[0..256) and ready area
  if (t == 0) ctrs[32768] = 0u;                 // ready counter
}

// ---------- K1: x (B,D,T) f32 -> xT[t][b][d] f16 ----------
__global__ __launch_bounds__(256) void k_xpose(const float* __restrict__ x,
                                               u16* __restrict__ xT) {
  __shared__ float lds[64][65];
  const int d0 = blockIdx.x * 64, t0 = blockIdx.y * 64, b = blockIdx.z;
  const int tid = threadIdx.x;
  const int tt = tid & 63, dr = tid >> 6;
  const float* xp = x + ((size_t)b * 512 + d0) * 512 + t0 + tt;
#pragma unroll
  for (int i = 0; i < 16; ++i) {
    int dd = i * 4 + dr;
    lds[dd][tt] = xp[(size_t)dd * 512];
  }
  __syncthreads();
  const int dp = tid & 31, rr = tid >> 5;
#pragma unroll
  for (int i = 0; i < 8; ++i) {
    int tt2 = i * 8 + rr;
    u32 lo = f2h(lds[dp * 2][tt2]);
    u32 hi = f2h(lds[dp * 2 + 1][tt2]);
    *(u32*)(xT + ((size_t)(t0 + tt2) * 64 + b) * 512 + d0 + dp * 2) = lo | (hi << 16);
  }
}

// ---------- K2: pack [W_ih | W_hh] rows into per-lane MFMA A-fragments (f16) ----------
// chunk c = (r*48 + ks)*4 + mt ; within-tile row m: gate=m&3, j=r*16+mt*4+(m>>2)
__global__ __launch_bounds__(256) void k_wfrag(const float* __restrict__ W_ih,
                                               const float* __restrict__ W_hh,
                                               u16* __restrict__ Wf) {
  int g = blockIdx.x * 256 + threadIdx.x;       // 786432 threads
  int lane = g & 63;
  int c  = g >> 6;                              // [0, 12288)
  int mt = c & 3;
  int cc = c >> 2;
  int ks = cc % 48;
  int r  = cc / 48;
  int m = lane & 15, q = lane >> 4;
  int gate = m & 3;
  int j = r * 16 + mt * 4 + (m >> 2);
  int row = gate * 1024 + j;
  const float* src = (ks < 16) ? (W_ih + (size_t)row * 512 + ks * 32 + q * 8)
                               : (W_hh + (size_t)row * 1024 + (ks - 16) * 32 + q * 8);
  union { u16 s[8]; uint4 v; } U;
#pragma unroll
  for (int i = 0; i < 8; ++i) U.s[i] = f2h(src[i]);
  *(uint4*)(Wf + ((size_t)c * 64 + lane) * 8) = U.v;
}

// ---------- K3: persistent cooperative recurrence ----------
// grid 256 = 4 groups x 64 blocks; block 512 = 8 waves; 1 block/CU.
// Wave w handles k-steps ks = {2w, 2w+1} (x) and {16+4w .. 16+4w+3} (h).
// Its h rows j in [128w, 128w+128) come from producer blocks r' in [8w, 8w+8)
// — disjoint across w, union over 8 waves = ALL 64 blocks of the group.
// FLAGS: ONE flag per producer block, flags[g*64+r], contiguous. The 4 reducer
// waves (w<4) each bump a monotonic LDS arrival counter after their vmcnt(0)
// h-store drain; the LAST arrival (old == 4t+3) publishes flags[g*64+r] = t+1.
// Consumer wave w polls flags[g*64+8w..+8) — 32 contiguous bytes, ONE 128B line
// per poll iteration (was 32 lines in the 2596.9us baseline). Cuts device-wide
// spin traffic ~32x (was ~95 LLC line-req/cyc ≈ saturation; congestion inflated
// every RTT in the serial h-exchange chain).
// Safety: flag >= t  =>  all 4 waves' h(t-1) stores ACKed at LLC before the
// last wave's ds_add (vmcnt(0) precedes it), which precedes the flag store.
// Buffer-overwrite: a block writes hnext only after its barrier, which needs
// all 8 waves' spins => all 64 group flags >= t => every block in the group
// passed its step t-1 barrier => completed its step t-1 h loads.
// THIS REVISION: x-part MFMAs (kl=0,1) hoisted ABOVE the spin (pinned via
// volatile asm) so they overlap the flag wait; LDS reduce is pairwise-tree
// (depth 3 instead of 7) to shorten the gate-math critical path.
__global__ __launch_bounds__(512, 2) void k_lstm(
    const u16* __restrict__ xT, const u16* __restrict__ Wf,
    u16* hbuf, u32* ctrs,
    const float* __restrict__ b_ih, const float* __restrict__ b_hh,
    const float* __restrict__ W_out, float* __restrict__ part) {
  __shared__ f32x4 red[2][8 * 4 * 64];    // [parity][wave][mt][lane], 64 KB
  __shared__ u32 arrive;                  // monotonic: 4 increments per step
  const int tid = threadIdx.x;
  const int w = tid >> 6, lane = tid & 63;
  const int blk = blockIdx.x, g = blk >> 6, r = blk & 63;
  const int bg0 = g * 16, j0 = r * 16;
  const int n = lane & 15, q = lane >> 4;

  // Step-invariant weights -> registers (AGPR-eligible on gfx950)
  f16x8 wfr[6][4];
#pragma unroll
  for (int kl = 0; kl < 6; ++kl) {
    int ks = (kl < 2) ? (2 * w + kl) : (16 + 4 * w + (kl - 2));
#pragma unroll
    for (int mt = 0; mt < 4; ++mt) {
      size_t c = ((size_t)r * 48 + ks) * 4 + mt;
      wfr[kl][mt] = *(const f16x8*)(Wf + (c * 64 + lane) * 8);
    }
  }

  float bias0 = 0.f, bias1 = 0.f, bias2 = 0.f, bias3 = 0.f, wout = 0.f;
  if (w < 4) {
    int j = j0 + w * 4 + q;
    bias0 = b_ih[j]        + b_hh[j];
    bias1 = b_ih[1024 + j] + b_hh[1024 + j];
    bias2 = b_ih[2048 + j] + b_hh[2048 + j];
    bias3 = b_ih[3072 + j] + b_hh[3072 + j];
    wout  = W_out[j];
  }

  u32* ready = ctrs + 32768;
  // this block's single publish flag
  u32* flagp = ctrs + ((u32)g * 64 + (u32)r);
  // poll pointer: lanes 0..7 poll this wave's 8 producers (contiguous, 1 line)
  const u32* fp = ctrs + ((u32)g * 64 + 8u * (u32)w + ((u32)lane & 7u));

  if (tid == 0) arrive = 0u;

  // One-time grid barrier: all Wf loads done before part[] overwrites Wf
  __syncthreads();                        // each wave drains vmcnt -> wfr in regs
  if (tid == 0) {
    __hip_atomic_fetch_add(ready, 1u, __ATOMIC_RELAXED, __HIP_MEMORY_SCOPE_AGENT);
    while (__hip_atomic_load(ready, __ATOMIC_RELAXED, __HIP_MEMORY_SCOPE_AGENT) < 256u)
      __builtin_amdgcn_s_sleep(8);
  }
  __syncthreads();
  // zero own out-partial slice part[t=tid][g][r][0..16) (plain stores -> own L2)
  {
    f32x4 z = {0.f, 0.f, 0.f, 0.f};
    f32x4* p4 = (f32x4*)&part[((size_t)(tid * 4 + g) * 64 + r) * 16];
    p4[0] = z; p4[1] = z; p4[2] = z; p4[3] = z;
  }
  __syncthreads();                        // drain zero stores before any atomicAdd
  asm volatile("" ::: "memory");

  u16* hb0 = hbuf;
  u16* hb1 = hbuf + 64 * 1024;
  float c_state = 0.f;
  const f32x4 zero = {0.f, 0.f, 0.f, 0.f};

  for (int t = 0; t < 512; ++t) {
    const u16* hcur = (t & 1) ? hb1 : hb0;
    u16* hnext      = (t & 1) ? hb0 : hb1;
    const u16* xtb  = xT + (size_t)t * 32768;

    // flag-independent x loads first (ks = 2w, 2w+1)
    f16x8 bfr[6];
#pragma unroll
    for (int kl = 0; kl < 2; ++kl)
      bfr[kl] = *(const f16x8*)(xtb + (bg0 + n) * 512 + (2 * w + kl) * 32 + q * 8);

    // x-part MFMAs BEFORE the spin: overlap with flag wait (off the h chain)
    f32x4 acc[4];
#pragma unroll
    for (int mt = 0; mt < 4; ++mt)
      acc[mt] = __builtin_amdgcn_mfma_f32_16x16x32_f16(wfr[0][mt], bfr[0], zero, 0, 0, 0);
#pragma unroll
    for (int mt = 0; mt < 4; ++mt)
      acc[mt] = __builtin_amdgcn_mfma_f32_16x16x32_f16(wfr[1][mt], bfr[1], acc[mt], 0, 0, 0);
    // pin: force the x-MFMAs to be scheduled before the spin (no sinking)
#pragma unroll
    for (int mt = 0; mt < 4; ++mt) asm volatile("" : "+v"(acc[mt]));

    // busy-poll own producers' block-flags: ONE cache line per iteration
    if (t > 0) {
      for (;;) {
        u32 f = 0xffffffffu;
        if (lane < 8)
          f = __hip_atomic_load(fp, __ATOMIC_RELAXED, __HIP_MEMORY_SCOPE_AGENT);
        if (__all((int)(f >= (u32)t))) break;
      }
    }
    asm volatile("" ::: "memory");   // no hoisting of h loads above the spin

    // h loads immediately after spin exit (ks-16 = 4w .. 4w+3)
#pragma unroll
    for (int kl = 2; kl < 6; ++kl) {
      const u64* p = (const u64*)(hcur + (bg0 + n) * 1024 + (4 * w + kl - 2) * 32 + q * 8);
      union { u64 u[2]; f16x8 v; } U;
      U.u[0] = __hip_atomic_load(p,     __ATOMIC_RELAXED, __HIP_MEMORY_SCOPE_AGENT);
      U.u[1] = __hip_atomic_load(p + 1, __ATOMIC_RELAXED, __HIP_MEMORY_SCOPE_AGENT);
      bfr[kl] = U.v;
    }

#pragma unroll
    for (int kl = 2; kl < 6; ++kl)
#pragma unroll
      for (int mt = 0; mt < 4; ++mt)
        acc[mt] = __builtin_amdgcn_mfma_f32_16x16x32_f16(wfr[kl][mt], bfr[kl], acc[mt], 0, 0, 0);

#pragma unroll
    for (int mt = 0; mt < 4; ++mt)
      red[t & 1][(w * 4 + mt) * 64 + lane] = acc[mt];
    __syncthreads();                      // the ONLY barrier per step

    if (w < 4) {
      const int mt = w;
      // pairwise-tree reduce: depth 3 instead of 7 on the gate critical path
      const f32x4* rp = &red[t & 1][mt * 64 + lane];   // wv stride = 256 f32x4
      f32x4 s01 = rp[0]    + rp[256];
      f32x4 s23 = rp[512]  + rp[768];
      f32x4 s45 = rp[1024] + rp[1280];
      f32x4 s67 = rp[1536] + rp[1792];
      f32x4 s = (s01 + s23) + (s45 + s67);
      // lane owns all 4 gates of (b = bg0+n, j = j0+mt*4+q): regs = i,f,g,o
      float gi = s.x + bias0, gf = s.y + bias1, gg = s.z + bias2, go = s.w + bias3;
      c_state = sigm(gf) * c_state + sigm(gi) * tanh_fast(gg);
      float h = sigm(go) * tanh_fast(c_state);
      // pack f16 pairs across quads, LLC-direct store to hnext[b][j]
      u32 hv = (u32)__builtin_bit_cast(u16, (_Float16)h);
      u32 other = (u32)__shfl_xor((int)hv, 16);
      if ((q & 1) == 0) {
        u32 packed = (hv & 0xffffu) | (other << 16);
        __hip_atomic_store((u32*)(hnext + (bg0 + n) * 1024 + j0 + mt * 4 + q), packed,
                           __ATOMIC_RELAXED, __HIP_MEMORY_SCOPE_AGENT);
      }
      // drain own h stores to LLC, then arrive; LAST of the 4 waves publishes
      asm volatile("s_waitcnt vmcnt(0)" ::: "memory");
      if (lane == 0) {
        u32 old = atomicAdd(&arrive, 1u);           // LDS, monotonic
        if (old == 4u * (u32)t + 3u)
          __hip_atomic_store(flagp, (u32)(t + 1),
                             __ATOMIC_RELAXED, __HIP_MEMORY_SCOPE_AGENT);
      }
      // fused out-projection partial (fire-and-forget, own-L2 atomic)
      float p = h * wout;
      p += __shfl_xor(p, 16);
      p += __shfl_xor(p, 32);
      if (lane < 16)
        __hip_atomic_fetch_add(&part[((size_t)(t * 4 + g) * 64 + r) * 16 + lane], p,
                               __ATOMIC_RELAXED, __HIP_MEMORY_SCOPE_WORKGROUP);
    }
  }
}

// ---------- K4: out[b][t] = b_out + sum_r part[t][g][r][b&15] ----------
__global__ __launch_bounds__(256) void k_out(const float* __restrict__ part,
                                             const float* __restrict__ b_out,
                                             float* __restrict__ out) {
  int gi = blockIdx.x * 256 + threadIdx.x;      // 32768 threads
  int t = gi >> 6, b = gi & 63, g = b >> 4, b16 = b & 15;
  const float* p = part + ((size_t)(t * 4 + g) * 64) * 16 + b16;
  float s = b_out[0];
#pragma unroll 8
  for (int r = 0; r < 64; ++r) s += p[r * 16];
  out[(size_t)b * 512 + t] = s;
}

extern "C" void kernel_launch(void* const* d_in, const int* in_sizes, int n_in,
                              void* d_out, int out_size, void* d_ws, size_t ws_size,
                              hipStream_t stream) {
  const float* x    = (const float*)d_in[0];
  const float* W_ih = (const float*)d_in[1];
  const float* W_hh = (const float*)d_in[2];
  const float* b_ih = (const float*)d_in[3];
  const float* b_hh = (const float*)d_in[4];
  const float* Wout = (const float*)d_in[5];
  const float* bout = (const float*)d_in[6];
  float* out = (float*)d_out;

  unsigned char* ws = (unsigned char*)d_ws;
  u16* xT   = (u16*)(ws + WS_XT_OFF);
  u16* Wf   = (u16*)(ws + WS_WF_OFF);
  u16* hbuf = (u16*)(ws + WS_HB_OFF);
  u32* ctrs = (u32*)(ws + WS_CTR_OFF);
  float* part = (float*)(ws + WS_WF_OFF);       // reuses Wf region after load

  k_init<<<128, 256, 0, stream>>>(hbuf, ctrs);
  k_xpose<<<dim3(8, 8, 64), 256, 0, stream>>>(x, xT);
  k_wfrag<<<3072, 256, 0, stream>>>(W_ih, W_hh, Wf);

  void* args[8] = {&xT, &Wf, &hbuf, &ctrs, &b_ih, &b_hh, &Wout, &part};
  hipLaunchCooperativeKernel((const void*)k_lstm, dim3(256), dim3(512), args, 0, stream);

  k_out<<<128, 256, 0, stream>>>(part, bout, out);
}